// Round 13
// baseline (853.047 us; speedup 1.0000x reference)
//
#include <hip/hip_runtime.h>

typedef _Float16 f16x8 __attribute__((ext_vector_type(8)));
typedef float f32x4 __attribute__((ext_vector_type(4)));

constexpr int D = 256;
constexpr int NUTT = 64;
constexpr int L = 512;
constexpr int G = 768;           // 3*D
constexpr int NBLK = 6;          // 128-col n-blocks over G=768
constexpr int NPROD = 192;       // persistent producer blocks
constexpr int NJOBS = 8 * NUTT * NBLK;     // 3072 jobs (64-row x 128-col)

// LDS-only barrier: orders ds_* ops across the workgroup WITHOUT draining
// vmcnt — global prefetch loads / wo16 stores stay in flight across steps.
__device__ __forceinline__ void lds_barrier() {
  asm volatile("s_waitcnt lgkmcnt(0)\n\ts_barrier" ::: "memory");
}

__device__ __forceinline__ float fast_rcp(float x) {
  return __builtin_amdgcn_rcpf(x);
}
__device__ __forceinline__ float sigm(float x) {
  return fast_rcp(1.0f + __expf(-x));
}
__device__ __forceinline__ float tanh_f(float x) {
  float ax = fabsf(x);
  float e = __expf(-2.0f * ax);
  float r = (1.0f - e) * fast_rcp(1.0f + e);
  return copysignf(r, x);
}

// chunk layout over the 8 rowblocks (64 steps each):
//   chunk 0 = rb0, chunk 1 = rb1, chunk 2 = rb2-3, chunk 3 = rb4-5,
//   chunk 4 = rb6-7.  Small early chunks cut the consumer lead-in.
__device__ __constant__ int c_chunk_of_rb[8] = {0, 1, 2, 2, 3, 3, 4, 4};

// ---------------------------------------------------------------------------
// Kernel A: pack Wih (f32) -> f16 hi/lo in MFMA fragment order (R9-verified,
// inverted map: thread = dst index, coalesced stores).
// Block 0 also zeroes the 512 producer-consumer flags (64B-padded).
// ---------------------------------------------------------------------------
__global__ __launch_bounds__(256) void pack_wih(
    const float* __restrict__ Wih, _Float16* __restrict__ hi,
    _Float16* __restrict__ lo, int* cnt) {
  if (blockIdx.x == 0) {
    cnt[threadIdx.x << 4] = 0;
    cnt[(threadIdx.x + 256) << 4] = 0;
  }
  const int d = blockIdx.x * 256 + threadIdx.x;    // grid = 768 blocks
  const int j = d & 7;
  const int l15 = (d >> 3) & 15;
  const int lk = (d >> 7) & 3;
  const int f = (d >> 9) & 7;
  const int it = d >> 12;
  const int g = 16 * it + l15;
  const int k = 32 * f + 8 * lk + j;
  float v = Wih[g * 256 + k];
  _Float16 h = (_Float16)v;
  hi[d] = h;
  lo[d] = (_Float16)(v - (float)h);
}

// ---------------------------------------------------------------------------
// Mega-kernel v13: NO-CO-RESIDENCY producer/consumer split.
// R12 localized the ~75 µs scan slowdown to producer blocks sharing CUs
// with consumers (1600 blocks / 2-per-CU capacity -> ~6 producer turns per
// consumer CU; setprio null => issue-side arbitration isn't fixable).
// Fix: grid = 256 blocks exactly — 64 consumers + 192 PERSISTENT producers
// each looping over 16 jobs (64 rows x 128 cols). Breadth-first dispatch
// (32 SEs x 8 CUs) puts one block per CU: co-residency is impossible.
// Jobs run rowblock-major == chunk-major; chunks {64,64,128,128,128} make
// chunk 0 only 384 jobs (~2 rounds ~25 µs lead-in).
// Handshake unchanged: release-add per (utt,chunk) after __syncthreads;
// consumer acquire-spins to the chunk's expected count {6,6,12,12,12}.
// Producers never wait -> deadlock-free under any placement.
// ---------------------------------------------------------------------------
__global__ __launch_bounds__(512, 2) void hran_mega(
    const int* __restrict__ tokens, const float* __restrict__ embed,
    const _Float16* __restrict__ whi, const _Float16* __restrict__ wlo,
    const float* __restrict__ bih,   // wg_bih
    const float* __restrict__ Whh,   // wg_Whh
    const float* __restrict__ bhh,   // wg_bhh
    const float* __restrict__ uaw,   // ua_w
    const float* __restrict__ sWih, const float* __restrict__ sbih,
    const float* __restrict__ sbhh,
    float* __restrict__ gx,          // [NUTT][L][G]
    _Float16* __restrict__ wo16,     // [NUTT][L][D] f16 h history
    int* cnt,                        // 512 flags, 64B-padded: [u][chunk]
    float* __restrict__ out) {       // [NUTT][D]
  __shared__ __align__(16) _Float16 hbuf[2][D];   // f16 h, double-buffered
  __shared__ float pre[3][D];                     // [comp][d] = aR/aZ/aN
  __shared__ float lg[L];
  __shared__ float red[16];
  __shared__ float part[D];
  __shared__ __align__(16) float ut[D];

  const int bx = blockIdx.x;
  const int t = threadIdx.x;
  const int w = t >> 6;               // wave 0..7
  const int lane = t & 63;
  const int l15 = lane & 15;
  const int lk = lane >> 4;

  if (bx >= NUTT) {
    // ============ persistent gemm producer: 16 jobs of 64x128 ============
    const int p = bx - NUTT;                   // 0..191
    const f16x8* Bh = (const f16x8*)whi;
    const f16x8* Bl = (const f16x8*)wlo;
    const int fragbase = lk * 16 + l15;
    const int wr = w & 3;                      // row-quarter within job
    const int wc = w >> 2;                     // col-half within job

    for (int J = p; J < NJOBS; J += NPROD) {   // rowblock-major == chunk-major
      const int rb = J / (NUTT * NBLK);        // 0..7 (64-step rowblock)
      const int rem = J % (NUTT * NBLK);
      const int u = rem / NBLK;
      const int nb = rem % NBLK;
      const int m0 = u * L + rb * 64;
      const int n0 = nb * 128 + wc * 64;
      const int it0 = nb * 8 + wc * 4;

      const int tok = tokens[m0 + 16 * wr + l15];
      const float* arow = embed + (size_t)tok * D;

      f32x4 acc[4] = {};
#pragma unroll
      for (int f = 0; f < 8; ++f) {
        const float* ap = arow + 32 * f + 8 * lk;
        float4 v0 = *(const float4*)(ap);
        float4 v1 = *(const float4*)(ap + 4);
        float av[8] = {v0.x, v0.y, v0.z, v0.w, v1.x, v1.y, v1.z, v1.w};
        f16x8 ahi, alo;
#pragma unroll
        for (int j = 0; j < 8; ++j) {
          _Float16 h = (_Float16)av[j];
          ahi[j] = h;
          alo[j] = (_Float16)(av[j] - (float)h);
        }
#pragma unroll
        for (int i = 0; i < 4; ++i) {
          const int frag = ((it0 + i) * 8 + f) * 64 + fragbase;
          f16x8 bhi = Bh[frag];
          f16x8 blo = Bl[frag];
          acc[i] = __builtin_amdgcn_mfma_f32_16x16x32_f16(ahi, bhi, acc[i], 0, 0, 0);
          acc[i] = __builtin_amdgcn_mfma_f32_16x16x32_f16(alo, bhi, acc[i], 0, 0, 0);
          acc[i] = __builtin_amdgcn_mfma_f32_16x16x32_f16(ahi, blo, acc[i], 0, 0, 0);
        }
      }
#pragma unroll
      for (int i = 0; i < 4; ++i) {
        const int n = n0 + 16 * i + l15;
        const float bb = bih[n];
#pragma unroll
        for (int reg = 0; reg < 4; ++reg) {
          const int m = m0 + 16 * wr + 4 * lk + reg;
          gx[(size_t)m * G + n] = acc[i][reg] + bb;
        }
      }
      __syncthreads();                 // drains all waves' vmcnt
      if (t == 0)
        __hip_atomic_fetch_add(&cnt[((u << 3) + c_chunk_of_rb[rb]) << 4], 1,
                               __ATOMIC_RELEASE, __HIP_MEMORY_SCOPE_AGENT);
    }
    return;
  }

  // ====================== gru consumer role ==============================
  const int b = bx;

  // ---- Bf[i][f][j] = Whh[96w + 16i + l15][32f + 8lk + j], f16 ----
  f16x8 Bf[6][8];
#pragma unroll
  for (int i = 0; i < 6; ++i) {
    const float* row = Whh + (size_t)(96 * w + 16 * i + l15) * D + 8 * lk;
#pragma unroll
    for (int f = 0; f < 8; ++f) {
      float4 v0 = *(const float4*)(row + 32 * f);
      float4 v1 = *(const float4*)(row + 32 * f + 4);
      Bf[i][f] = f16x8{(_Float16)v0.x, (_Float16)v0.y,
                       (_Float16)v0.z, (_Float16)v0.w,
                       (_Float16)v1.x, (_Float16)v1.y,
                       (_Float16)v1.z, (_Float16)v1.w};
    }
  }

  float bR = 0.0f, bZ = 0.0f, bN = 0.0f;
  float gr = 0.0f, gz = 0.0f, gn = 0.0f;
  float hprev = 0.0f;
  float* gxb = gx + (size_t)b * L * G;
  _Float16* wob = wo16 + (size_t)b * L * D;
  if (t < 256) {
    bR = bhh[t]; bZ = bhh[D + t]; bN = bhh[2 * D + t];
    hbuf[0][t] = (_Float16)0.0f;
  }
  __syncthreads();

  const int cstart[5] = {0, 64, 128, 256, 384};
  const int csize[5]  = {64, 64, 128, 128, 128};
  const int cneed[5]  = {6, 6, 12, 12, 12};

  for (int c = 0; c < 5; ++c) {
    // wait for this utterance's chunk c
    if (t == 0) {
      while (__hip_atomic_load(&cnt[((b << 3) + c) << 4],
                               __ATOMIC_ACQUIRE,
                               __HIP_MEMORY_SCOPE_AGENT) < cneed[c])
        __builtin_amdgcn_s_sleep(8);
    }
    __syncthreads();
    __threadfence();
    if (t < 256) {                   // chunk-entry g* load
      const float* gc = gxb + (size_t)cstart[c] * G;
      gr = gc[t]; gz = gc[D + t]; gn = gc[2 * D + t];
    }

    const int cs = csize[c];
    for (int tsl = 0; tsl < cs; ++tsl) {
      const int ts = cstart[c] + tsl;
      const int cur = ts & 1;
      const _Float16* hb = hbuf[cur];
      f16x8 A[8];
#pragma unroll
      for (int f = 0; f < 8; ++f)
        A[f] = *(const f16x8*)(hb + 32 * f + 8 * lk);

#pragma unroll
      for (int i = 0; i < 6; ++i) {
        f32x4 acc = {0.0f, 0.0f, 0.0f, 0.0f};
#pragma unroll
        for (int f = 0; f < 8; ++f)
          acc = __builtin_amdgcn_mfma_f32_16x16x32_f16(A[f], Bf[i][f], acc,
                                                       0, 0, 0);
        if (lk == 0) {                // all D rows equal; lanes 0-15 publish
          const int n = 96 * w + 16 * i + l15;
          pre[n >> 8][n & 255] = acc[0];
        }
      }
      lds_barrier();

      if (t < 256) {
        float aR = pre[0][t], aZ = pre[1][t], aNp = pre[2][t];
        float r = sigm(gr + aR + bR);
        float z = sigm(gz + aZ + bZ);
        float nn = tanh_f(gn + r * (aNp + bN));
        float hn = fmaf(z, hprev - nn, nn);    // (1-z)*n + z*h
        hprev = hn;
        _Float16 hf = (_Float16)hn;
        hbuf[cur ^ 1][t] = hf;
        wob[(size_t)ts * D + t] = hf;          // f16 history (coalesced)
        if (tsl + 1 < cs) {                    // within chunk: prefetch
          const float* gxn = gxb + (size_t)(ts + 1) * G;
          gr = gxn[t]; gz = gxn[D + t]; gn = gxn[2 * D + t];
        }
      }
      lds_barrier();
    }
  }

  // ===== fused epilogue: attn-pool (f16 history) + sentence GRU =====
  asm volatile("s_waitcnt vmcnt(0)" ::: "memory");   // wo16 stores done
  __syncthreads();

  // logits: wave w handles rows [64w, 64w+64); f16 rows, 512B each
  {
    const float ua0 = uaw[lane], ua1 = uaw[lane + 64];
    const float ua2 = uaw[lane + 128], ua3 = uaw[lane + 192];
    for (int r = 0; r < 64; ++r) {
      const int tt = 64 * w + r;
      const _Float16* row = wob + (size_t)tt * D;
      float p = (float)row[lane] * ua0 + (float)row[lane + 64] * ua1 +
                (float)row[lane + 128] * ua2 + (float)row[lane + 192] * ua3;
#pragma unroll
      for (int off = 32; off; off >>= 1) p += __shfl_down(p, off);
      if (lane == 0) lg[tt] = p;               // ua_b cancels in softmax
    }
  }
  __syncthreads();

  // softmax over 512 logits (thread t owns lg[t])
  {
    float v = lg[t];
    float m = v;
#pragma unroll
    for (int off = 32; off; off >>= 1) m = fmaxf(m, __shfl_xor(m, off));
    if (lane == 0) red[w] = m;
    __syncthreads();
    m = red[0];
#pragma unroll
    for (int i = 1; i < 8; ++i) m = fmaxf(m, red[i]);
    float e = __expf(v - m);
    float s = e;
#pragma unroll
    for (int off = 32; off; off >>= 1) s += __shfl_xor(s, off);
    if (lane == 0) red[8 + w] = s;
    __syncthreads();
    s = red[8];
#pragma unroll
    for (int i = 9; i < 16; ++i) s += red[i];
    lg[t] = e * (1.0f / s);
  }
  __syncthreads();

  // weighted sum over f16 history: half 0 sums ts in [0,256), half 1 rest
  {
    const int d = t & 255, half = t >> 8;
    float acc = 0.0f;
    const _Float16* bbp = wob + (size_t)half * 256 * D;
    const float* lgh = lg + half * 256;
#pragma unroll 4
    for (int k = 0; k < 256; ++k)
      acc = fmaf(lgh[k], (float)bbp[(size_t)k * D + d], acc);
    if (half == 1) part[d] = acc;
    __syncthreads();
    if (half == 0) ut[d] = acc + part[d];
    __syncthreads();
  }

  // sentence GRU (T=1, h0=0) -> out = (1-z)*n
  if (t < 256) {
    const int d = t;
    const float* wr = sWih + (size_t)d * D;
    const float* wz = sWih + (size_t)(D + d) * D;
    const float* wn = sWih + (size_t)(2 * D + d) * D;
    float ar = 0.0f, az = 0.0f, an = 0.0f;
    for (int k = 0; k < D; k += 4) {
      float4 vr = *(const float4*)(wr + k);
      float4 vz = *(const float4*)(wz + k);
      float4 vn = *(const float4*)(wn + k);
      float u0 = ut[k], u1 = ut[k + 1], u2 = ut[k + 2], u3 = ut[k + 3];
      ar += vr.x * u0 + vr.y * u1 + vr.z * u2 + vr.w * u3;
      az += vz.x * u0 + vz.y * u1 + vz.z * u2 + vz.w * u3;
      an += vn.x * u0 + vn.y * u1 + vn.z * u2 + vn.w * u3;
    }
    float r = sigm(ar + sbih[d] + sbhh[d]);
    float z = sigm(az + sbih[D + d] + sbhh[D + d]);
    float n = tanh_f(an + sbih[2 * D + d] + r * sbhh[2 * D + d]);
    out[(size_t)b * D + d] = (1.0f - z) * n;
  }
}

// ---------------------------------------------------------------------------
extern "C" void kernel_launch(void* const* d_in, const int* in_sizes, int n_in,
                              void* d_out, int out_size, void* d_ws, size_t ws_size,
                              hipStream_t stream) {
  const int* tokens    = (const int*)d_in[0];
  const float* embed   = (const float*)d_in[1];
  const float* wg_Wih  = (const float*)d_in[2];
  const float* wg_Whh  = (const float*)d_in[3];
  const float* wg_bih  = (const float*)d_in[4];
  const float* wg_bhh  = (const float*)d_in[5];
  const float* ua_w    = (const float*)d_in[6];
  // d_in[7] ua_b: softmax shift-invariant -> unused
  const float* sg_Wih  = (const float*)d_in[8];
  // d_in[9] sg_Whh: h0 == 0 -> unused
  const float* sg_bih  = (const float*)d_in[10];
  const float* sg_bhh  = (const float*)d_in[11];
  // d_in[12..13] da_w/da_b: softmax over T=1 -> unused
  float* out = (float*)d_out;

  char* ws = (char*)d_ws;
  const size_t GXB = (size_t)NUTT * L * G * 4;                 // 96 MB
  float* gx = (float*)ws;
  _Float16* whi = (_Float16*)(ws + GXB);                       // 384 KB
  _Float16* wlo = whi + (size_t)G * D;                         // 384 KB
  int* cnt = (int*)(ws + GXB + (size_t)2 * G * D * 2);         // 32 KB flags
  _Float16* wo16 = (_Float16*)(ws + GXB + (size_t)2 * G * D * 2 + 32768);

  pack_wih<<<G, 256, 0, stream>>>(wg_Wih, whi, wlo, cnt);
  hran_mega<<<NUTT + NPROD, 512, 0, stream>>>(
      tokens, embed, whi, wlo, wg_bih, wg_Whh, wg_bhh, ua_w,
      sg_Wih, sg_bih, sg_bhh, gx, wo16, cnt, out);
}

// Round 14
// 774.600 us; speedup vs baseline: 1.1013x; 1.1013x over previous
//
#include <hip/hip_runtime.h>

typedef _Float16 f16x8 __attribute__((ext_vector_type(8)));
typedef float f32x4 __attribute__((ext_vector_type(4)));

constexpr int D = 256;
constexpr int NUTT = 64;
constexpr int L = 512;
constexpr int G = 768;           // 3*D
constexpr int CHUNK = 128;       // timesteps per producer chunk
constexpr int NCH = L / CHUNK;   // 4 chunks per utterance
constexpr int NBLK = 6;          // 128-col n-blocks over G=768
constexpr int NGEMM = NCH * NUTT * NBLK;   // 1536 producer blocks

// LDS-only barrier: orders ds_* ops across the workgroup WITHOUT draining
// vmcnt — global prefetch loads / wo16 stores stay in flight across steps.
__device__ __forceinline__ void lds_barrier() {
  asm volatile("s_waitcnt lgkmcnt(0)\n\ts_barrier" ::: "memory");
}

__device__ __forceinline__ float fast_rcp(float x) {
  return __builtin_amdgcn_rcpf(x);
}
__device__ __forceinline__ float sigm(float x) {
  return fast_rcp(1.0f + __expf(-x));
}
__device__ __forceinline__ float tanh_f(float x) {
  float ax = fabsf(x);
  float e = __expf(-2.0f * ax);
  float r = (1.0f - e) * fast_rcp(1.0f + e);
  return copysignf(r, x);
}

// ---------------------------------------------------------------------------
// Kernel A: pack Wih (f32) -> f16 hi/lo in MFMA fragment order (R9-verified,
// inverted map: thread = dst index, coalesced stores).
// Block 0 also zeroes the producer-consumer chunk flags (64B-padded).
// ---------------------------------------------------------------------------
__global__ __launch_bounds__(256) void pack_wih(
    const float* __restrict__ Wih, _Float16* __restrict__ hi,
    _Float16* __restrict__ lo, int* cnt) {
  if (blockIdx.x == 0) cnt[threadIdx.x << 4] = 0;
  const int d = blockIdx.x * 256 + threadIdx.x;    // grid = 768 blocks
  const int j = d & 7;
  const int l15 = (d >> 3) & 15;
  const int lk = (d >> 7) & 3;
  const int f = (d >> 9) & 7;
  const int it = d >> 12;
  const int g = 16 * it + l15;
  const int k = 32 * f + 8 * lk + j;
  float v = Wih[g * 256 + k];
  _Float16 h = (_Float16)v;
  hi[d] = h;
  lo[d] = (_Float16)(v - (float)h);
}

// ---------------------------------------------------------------------------
// Mega-kernel — R11 structure (verified best: mega 696, no setprio) plus ONE
// change: a 75 KiB LDS pad raises the static LDS footprint above 80 KiB so
// the HW occupancy limit is 1 BLOCK PER CU for every block of this kernel.
// R13 proved placement can't be steered by grid sizing (scheduler packed
// persistent producers onto consumer CUs: 775 µs); resource limits are the
// only enforceable placement tool. With 1/CU: consumers (blocks 0-63,
// dispatched first) each own a CU exclusively; the 1536 transient producers
// cycle 1/CU over the other 192 CUs (8 rounds ~15 µs; chunk 0 = 2 rounds).
// Only L2/HBM bandwidth is still shared — CU issue interference is gone.
// ---------------------------------------------------------------------------
__global__ __launch_bounds__(512, 1) void hran_mega(
    const int* __restrict__ tokens, const float* __restrict__ embed,
    const _Float16* __restrict__ whi, const _Float16* __restrict__ wlo,
    const float* __restrict__ bih,   // wg_bih
    const float* __restrict__ Whh,   // wg_Whh
    const float* __restrict__ bhh,   // wg_bhh
    const float* __restrict__ uaw,   // ua_w
    const float* __restrict__ sWih, const float* __restrict__ sbih,
    const float* __restrict__ sbhh,
    float* __restrict__ gx,          // [NUTT][L][G]
    _Float16* __restrict__ wo16,     // [NUTT][L][D] f16 h history
    int* cnt,                        // 256 flags, 64B-padded
    float* __restrict__ out) {       // [NUTT][D]
  __shared__ __align__(16) _Float16 hbuf[2][D];   // f16 h, double-buffered
  __shared__ float pre[3][D];                     // [comp][d] = aR/aZ/aN
  __shared__ float lg[L];
  __shared__ float red[16];
  __shared__ float part[D];
  __shared__ __align__(16) float ut[D];
  // Occupancy limiter: total static LDS > 80 KiB -> 1 block/CU (160 KiB/CU).
  __shared__ __align__(16) char lds_pad[76800];

  const int bx = blockIdx.x;
  const int t = threadIdx.x;
  if (t == 0) ((volatile char*)lds_pad)[0] = 1;   // keep pad live
  const int w = t >> 6;               // wave 0..7
  const int lane = t & 63;
  const int l15 = lane & 15;
  const int lk = lane >> 4;

  if (bx >= NUTT) {
    // =================== gemm producer role (R7/R8-verified) =============
    const int gbx = bx - NUTT;
    const int c = gbx / (NUTT * NBLK);         // chunk-major
    const int rem = gbx % (NUTT * NBLK);
    const int u = rem / NBLK;
    const int nb = rem % NBLK;
    const int m0 = u * L + c * CHUNK;          // 128 rows (8 waves x 16)
    const int n0 = nb * 128;
    const int it0 = nb * 8;

    const int tok = tokens[m0 + 16 * w + l15];
    const float* arow = embed + (size_t)tok * D;
    const f16x8* Bh = (const f16x8*)whi;
    const f16x8* Bl = (const f16x8*)wlo;
    const int fragbase = lk * 16 + l15;

    f32x4 acc[8] = {};
#pragma unroll
    for (int f = 0; f < 8; ++f) {
      const float* ap = arow + 32 * f + 8 * lk;
      float4 v0 = *(const float4*)(ap);
      float4 v1 = *(const float4*)(ap + 4);
      float av[8] = {v0.x, v0.y, v0.z, v0.w, v1.x, v1.y, v1.z, v1.w};
      f16x8 ahi, alo;
#pragma unroll
      for (int j = 0; j < 8; ++j) {
        _Float16 h = (_Float16)av[j];
        ahi[j] = h;
        alo[j] = (_Float16)(av[j] - (float)h);
      }
#pragma unroll
      for (int i = 0; i < 8; ++i) {
        const int frag = ((it0 + i) * 8 + f) * 64 + fragbase;
        f16x8 bhi = Bh[frag];
        f16x8 blo = Bl[frag];
        acc[i] = __builtin_amdgcn_mfma_f32_16x16x32_f16(ahi, bhi, acc[i], 0, 0, 0);
        acc[i] = __builtin_amdgcn_mfma_f32_16x16x32_f16(alo, bhi, acc[i], 0, 0, 0);
        acc[i] = __builtin_amdgcn_mfma_f32_16x16x32_f16(ahi, blo, acc[i], 0, 0, 0);
      }
    }
#pragma unroll
    for (int i = 0; i < 8; ++i) {
      const int n = n0 + 16 * i + l15;
      const float bb = bih[n];
#pragma unroll
      for (int reg = 0; reg < 4; ++reg) {
        const int m = m0 + 16 * w + 4 * lk + reg;
        gx[(size_t)m * G + n] = acc[i][reg] + bb;
      }
    }
    __syncthreads();                 // drains vmcnt: all stores issued
    if (t == 0)
      __hip_atomic_fetch_add(&cnt[((u << 2) + c) << 4], 1,
                             __ATOMIC_RELEASE, __HIP_MEMORY_SCOPE_AGENT);
    return;
  }

  // ====================== gru consumer role ==============================
  const int b = bx;

  // ---- Bf[i][f][j] = Whh[96w + 16i + l15][32f + 8lk + j], f16 ----
  f16x8 Bf[6][8];
#pragma unroll
  for (int i = 0; i < 6; ++i) {
    const float* row = Whh + (size_t)(96 * w + 16 * i + l15) * D + 8 * lk;
#pragma unroll
    for (int f = 0; f < 8; ++f) {
      float4 v0 = *(const float4*)(row + 32 * f);
      float4 v1 = *(const float4*)(row + 32 * f + 4);
      Bf[i][f] = f16x8{(_Float16)v0.x, (_Float16)v0.y,
                       (_Float16)v0.z, (_Float16)v0.w,
                       (_Float16)v1.x, (_Float16)v1.y,
                       (_Float16)v1.z, (_Float16)v1.w};
    }
  }

  float bR = 0.0f, bZ = 0.0f, bN = 0.0f;
  float gr = 0.0f, gz = 0.0f, gn = 0.0f;
  float hprev = 0.0f;
  float* gxb = gx + (size_t)b * L * G;
  _Float16* wob = wo16 + (size_t)b * L * D;
  if (t < 256) {
    bR = bhh[t]; bZ = bhh[D + t]; bN = bhh[2 * D + t];
    hbuf[0][t] = (_Float16)0.0f;
  }
  __syncthreads();

  for (int c = 0; c < NCH; ++c) {
    // wait for this utterance's chunk c (6 producer blocks)
    if (t == 0) {
      while (__hip_atomic_load(&cnt[((b << 2) + c) << 4],
                               __ATOMIC_ACQUIRE,
                               __HIP_MEMORY_SCOPE_AGENT) < NBLK)
        __builtin_amdgcn_s_sleep(8);
    }
    __syncthreads();
    __threadfence();
    if (t < 256) {                   // chunk-entry g* load
      const float* gc = gxb + (size_t)(CHUNK * c) * G;
      gr = gc[t]; gz = gc[D + t]; gn = gc[2 * D + t];
    }

    for (int tsl = 0; tsl < CHUNK; ++tsl) {
      const int ts = CHUNK * c + tsl;
      const int cur = ts & 1;
      const _Float16* hb = hbuf[cur];
      f16x8 A[8];
#pragma unroll
      for (int f = 0; f < 8; ++f)
        A[f] = *(const f16x8*)(hb + 32 * f + 8 * lk);

#pragma unroll
      for (int i = 0; i < 6; ++i) {
        f32x4 acc = {0.0f, 0.0f, 0.0f, 0.0f};
#pragma unroll
        for (int f = 0; f < 8; ++f)
          acc = __builtin_amdgcn_mfma_f32_16x16x32_f16(A[f], Bf[i][f], acc,
                                                       0, 0, 0);
        if (lk == 0) {                // all D rows equal; lanes 0-15 publish
          const int n = 96 * w + 16 * i + l15;
          pre[n >> 8][n & 255] = acc[0];
        }
      }
      lds_barrier();

      if (t < 256) {
        float aR = pre[0][t], aZ = pre[1][t], aNp = pre[2][t];
        float r = sigm(gr + aR + bR);
        float z = sigm(gz + aZ + bZ);
        float nn = tanh_f(gn + r * (aNp + bN));
        float hn = fmaf(z, hprev - nn, nn);    // (1-z)*n + z*h
        hprev = hn;
        _Float16 hf = (_Float16)hn;
        hbuf[cur ^ 1][t] = hf;
        wob[(size_t)ts * D + t] = hf;          // f16 history (coalesced)
        const int tn = ts + 1;
        if (tn & (CHUNK - 1)) {                // within chunk: prefetch
          const float* gxn = gxb + (size_t)tn * G;
          gr = gxn[t]; gz = gxn[D + t]; gn = gxn[2 * D + t];
        }
      }
      lds_barrier();
    }
  }

  // ===== fused epilogue: attn-pool (f16 history) + sentence GRU =====
  asm volatile("s_waitcnt vmcnt(0)" ::: "memory");   // wo16 stores done
  __syncthreads();

  // logits: wave w handles rows [64w, 64w+64); f16 rows, 512B each
  {
    const float ua0 = uaw[lane], ua1 = uaw[lane + 64];
    const float ua2 = uaw[lane + 128], ua3 = uaw[lane + 192];
    for (int r = 0; r < 64; ++r) {
      const int tt = 64 * w + r;
      const _Float16* row = wob + (size_t)tt * D;
      float p = (float)row[lane] * ua0 + (float)row[lane + 64] * ua1 +
                (float)row[lane + 128] * ua2 + (float)row[lane + 192] * ua3;
#pragma unroll
      for (int off = 32; off; off >>= 1) p += __shfl_down(p, off);
      if (lane == 0) lg[tt] = p;               // ua_b cancels in softmax
    }
  }
  __syncthreads();

  // softmax over 512 logits (thread t owns lg[t])
  {
    float v = lg[t];
    float m = v;
#pragma unroll
    for (int off = 32; off; off >>= 1) m = fmaxf(m, __shfl_xor(m, off));
    if (lane == 0) red[w] = m;
    __syncthreads();
    m = red[0];
#pragma unroll
    for (int i = 1; i < 8; ++i) m = fmaxf(m, red[i]);
    float e = __expf(v - m);
    float s = e;
#pragma unroll
    for (int off = 32; off; off >>= 1) s += __shfl_xor(s, off);
    if (lane == 0) red[8 + w] = s;
    __syncthreads();
    s = red[8];
#pragma unroll
    for (int i = 9; i < 16; ++i) s += red[i];
    lg[t] = e * (1.0f / s);
  }
  __syncthreads();

  // weighted sum over f16 history: half 0 sums ts in [0,256), half 1 rest
  {
    const int d = t & 255, half = t >> 8;
    float acc = 0.0f;
    const _Float16* bbp = wob + (size_t)half * 256 * D;
    const float* lgh = lg + half * 256;
#pragma unroll 4
    for (int k = 0; k < 256; ++k)
      acc = fmaf(lgh[k], (float)bbp[(size_t)k * D + d], acc);
    if (half == 1) part[d] = acc;
    __syncthreads();
    if (half == 0) ut[d] = acc + part[d];
    __syncthreads();
  }

  // sentence GRU (T=1, h0=0) -> out = (1-z)*n
  if (t < 256) {
    const int d = t;
    const float* wr = sWih + (size_t)d * D;
    const float* wz = sWih + (size_t)(D + d) * D;
    const float* wn = sWih + (size_t)(2 * D + d) * D;
    float ar = 0.0f, az = 0.0f, an = 0.0f;
    for (int k = 0; k < D; k += 4) {
      float4 vr = *(const float4*)(wr + k);
      float4 vz = *(const float4*)(wz + k);
      float4 vn = *(const float4*)(wn + k);
      float u0 = ut[k], u1 = ut[k + 1], u2 = ut[k + 2], u3 = ut[k + 3];
      ar += vr.x * u0 + vr.y * u1 + vr.z * u2 + vr.w * u3;
      az += vz.x * u0 + vz.y * u1 + vz.z * u2 + vz.w * u3;
      an += vn.x * u0 + vn.y * u1 + vn.z * u2 + vn.w * u3;
    }
    float r = sigm(ar + sbih[d] + sbhh[d]);
    float z = sigm(az + sbih[D + d] + sbhh[D + d]);
    float n = tanh_f(an + sbih[2 * D + d] + r * sbhh[2 * D + d]);
    out[(size_t)b * D + d] = (1.0f - z) * n;
  }
}

// ---------------------------------------------------------------------------
extern "C" void kernel_launch(void* const* d_in, const int* in_sizes, int n_in,
                              void* d_out, int out_size, void* d_ws, size_t ws_size,
                              hipStream_t stream) {
  const int* tokens    = (const int*)d_in[0];
  const float* embed   = (const float*)d_in[1];
  const float* wg_Wih  = (const float*)d_in[2];
  const float* wg_Whh  = (const float*)d_in[3];
  const float* wg_bih  = (const float*)d_in[4];
  const float* wg_bhh  = (const float*)d_in[5];
  const float* ua_w    = (const float*)d_in[6];
  // d_in[7] ua_b: softmax shift-invariant -> unused
  const float* sg_Wih  = (const float*)d_in[8];
  // d_in[9] sg_Whh: h0 == 0 -> unused
  const float* sg_bih  = (const float*)d_in[10];
  const float* sg_bhh  = (const float*)d_in[11];
  // d_in[12..13] da_w/da_b: softmax over T=1 -> unused
  float* out = (float*)d_out;

  char* ws = (char*)d_ws;
  const size_t GXB = (size_t)NUTT * L * G * 4;                 // 96 MB
  float* gx = (float*)ws;
  _Float16* whi = (_Float16*)(ws + GXB);                       // 384 KB
  _Float16* wlo = whi + (size_t)G * D;                         // 384 KB
  int* cnt = (int*)(ws + GXB + (size_t)2 * G * D * 2);         // 16 KB flags
  _Float16* wo16 = (_Float16*)(ws + GXB + (size_t)2 * G * D * 2 + 16384);

  pack_wih<<<G, 256, 0, stream>>>(wg_Wih, whi, wlo, cnt);
  hran_mega<<<NUTT + NGEMM, 512, 0, stream>>>(
      tokens, embed, whi, wlo, wg_bih, wg_Whh, wg_bhh, ua_w,
      sg_Wih, sg_bih, sg_bhh, gx, wo16, cnt, out);
}